// Round 2
// baseline (211.784 us; speedup 1.0000x reference)
//
#include <hip/hip_runtime.h>

#define NPTS 200000
#define MWORDS 25000

// ---------- kernel 1: mask prefix scan + camera constants ----------
__global__ void scan_kernel(const int* __restrict__ mask, int* __restrict__ prefix,
                            float* __restrict__ rview, float* __restrict__ cam,
                            const float* __restrict__ viewmats,
                            const float* __restrict__ Ks,
                            const int* __restrict__ pw, const int* __restrict__ ph) {
    const int bc = blockIdx.x;      // 0..7  (b*4+c)
    const int t  = threadIdx.x;     // 0..1023
    const int base = bc * MWORDS;
    const int WPT = 25;             // 1024*25 = 25600 >= 25000
    const int start = t * WPT;

    int cnt = 0;
    for (int i = 0; i < WPT; i++) {
        int w = start + i;
        if (w < MWORDS) cnt += __popc(mask[base + w]);
    }
    __shared__ int sums[1024];
    sums[t] = cnt;
    __syncthreads();
    for (int off = 1; off < 1024; off <<= 1) {
        int v = (t >= off) ? sums[t - off] : 0;
        __syncthreads();
        sums[t] += v;
        __syncthreads();
    }
    int run = sums[t] - cnt;  // exclusive prefix over threads
    for (int i = 0; i < WPT; i++) {
        int w = start + i;
        if (w < MWORDS) { prefix[base + w] = run; run += __popc(mask[base + w]); }
    }

    if (bc == 0 && t < 72) rview[t] = 0.f;   // zero v_Rview accumulator

    if (t == 0) {
        float* cp = cam + bc * 20;
        const int vbase = bc * 16;
        for (int i = 0; i < 3; i++) {
            for (int j = 0; j < 3; j++) cp[i*3 + j] = viewmats[vbase + i*4 + j];
            cp[9 + i] = viewmats[vbase + i*4 + 3];
        }
        const int kbase = bc * 9;
        float fx = Ks[kbase + 0], fy = Ks[kbase + 4];
        float cx = Ks[kbase + 2], cy = Ks[kbase + 5];
        int wi = *pw, hi = *ph;
        float W = (wi >= 1 && wi <= (1 << 20)) ? (float)wi : __int_as_float(wi);
        float H = (hi >= 1 && hi <= (1 << 20)) ? (float)hi : __int_as_float(hi);
        float tanx = 0.5f * W / fx, tany = 0.5f * H / fy;
        cp[12] = fx; cp[13] = fy;
        cp[14] = (W - cx) / fx + 0.3f * tanx;   // lim_x_pos
        cp[15] = cx / fx + 0.3f * tanx;         // lim_x_neg
        cp[16] = (H - cy) / fy + 0.3f * tany;   // lim_y_pos
        cp[17] = cy / fy + 0.3f * tany;         // lim_y_neg
    }
}

// ---------- kernel 2: main backward ----------
__global__ __launch_bounds__(256) void main_kernel(
    const float* __restrict__ means,
    const float* __restrict__ quats,
    const float* __restrict__ scales,
    const float* __restrict__ conics,
    const float* __restrict__ v_m2d,
    const float* __restrict__ v_dep,
    const float* __restrict__ v_con,
    const float* __restrict__ v_col,
    const float* __restrict__ v_op,
    const int* __restrict__ mask,
    const int* __restrict__ prefix,
    const float* __restrict__ cam,
    float* __restrict__ rview_acc,
    float* __restrict__ out)
{
    const int O_PW = 0, O_QU = 1200000, O_SC = 2800000, O_CL = 4000072, O_OP = 5200072;
    const int b = blockIdx.y;
    const int n = blockIdx.x * 256 + threadIdx.x;
    const bool act = (n < NPTS);

    float rv[4][9];
#pragma unroll
    for (int c = 0; c < 4; c++)
#pragma unroll
        for (int k = 0; k < 9; k++) rv[c][k] = 0.f;

    float H00=0,H01=0,H02=0,H11=0,H12=0,H22=0;
    float vpw0=0,vpw1=0,vpw2=0;
    float vcl0=0,vcl1=0,vcl2=0, vopo=0;
    float qw=0,qx=0,qy=0,qz=0, inv_norm=1.f;
    float R00=0,R01=0,R02=0,R10=0,R11=0,R12=0,R20=0,R21=0,R22=0;
    float M00=0,M01=0,M02=0,M10=0,M11=0,M12=0,M20=0,M21=0,M22=0;
    float cv00=0,cv01=0,cv02=0,cv11=0,cv12=0,cv22=0;
    float mn0=0,mn1=0,mn2=0, sc0=0,sc1=0,sc2=0;

    if (act) {
        mn0 = means[(b*3+0)*NPTS + n];
        mn1 = means[(b*3+1)*NPTS + n];
        mn2 = means[(b*3+2)*NPTS + n];
        float q0 = quats[(b*4+0)*NPTS + n];
        float q1 = quats[(b*4+1)*NPTS + n];
        float q2 = quats[(b*4+2)*NPTS + n];
        float q3 = quats[(b*4+3)*NPTS + n];
        sc0 = scales[(b*3+0)*NPTS + n];
        sc1 = scales[(b*3+1)*NPTS + n];
        sc2 = scales[(b*3+2)*NPTS + n];
        inv_norm = rsqrtf(q0*q0 + q1*q1 + q2*q2 + q3*q3);
        qw = q0*inv_norm; qx = q1*inv_norm; qy = q2*inv_norm; qz = q3*inv_norm;
        R00 = 1.f - 2.f*(qy*qy + qz*qz); R01 = 2.f*(qx*qy - qw*qz); R02 = 2.f*(qx*qz + qw*qy);
        R10 = 2.f*(qx*qy + qw*qz); R11 = 1.f - 2.f*(qx*qx + qz*qz); R12 = 2.f*(qy*qz - qw*qx);
        R20 = 2.f*(qx*qz - qw*qy); R21 = 2.f*(qy*qz + qw*qx); R22 = 1.f - 2.f*(qx*qx + qy*qy);
        M00 = R00*sc0; M01 = R01*sc1; M02 = R02*sc2;
        M10 = R10*sc0; M11 = R11*sc1; M12 = R12*sc2;
        M20 = R20*sc0; M21 = R21*sc1; M22 = R22*sc2;
        cv00 = M00*M00 + M01*M01 + M02*M02;
        cv01 = M00*M10 + M01*M11 + M02*M12;
        cv02 = M00*M20 + M01*M21 + M02*M22;
        cv11 = M10*M10 + M11*M11 + M12*M12;
        cv12 = M10*M20 + M11*M21 + M12*M22;
        cv22 = M20*M20 + M21*M21 + M22*M22;

#pragma unroll
        for (int c = 0; c < 4; c++) {
            const int bc = b*4 + c;
            const float* cp = cam + bc*20;
            const float V00=cp[0],V01=cp[1],V02=cp[2],V10=cp[3],V11=cp[4],V12=cp[5],V20=cp[6],V21=cp[7],V22=cp[8];
            const float t0=cp[9], t1=cp[10], t2=cp[11];
            const float fx=cp[12], fy=cp[13], lxp=cp[14], lxn=cp[15], lyp=cp[16], lyn=cp[17];
            const int w_ = n >> 3, bit = n & 7;
            const int word = mask[bc*MWORDS + w_];
            if ((word >> bit) & 1) {
                const int r = prefix[bc*MWORDS + w_] + __popc(word & ((1 << bit) - 1));
                const int base3 = bc*3*NPTS, base2 = bc*2*NPTS, base1 = bc*NPTS;
                float g_c0 = v_con[base3 + r];
                float g_c1 = v_con[base3 + NPTS + r];
                float g_c2 = v_con[base3 + 2*NPTS + r];
                float g_m0 = v_m2d[base2 + r];
                float g_m1 = v_m2d[base2 + NPTS + r];
                float g_d  = v_dep[base1 + r];
                float g_l0 = v_col[base3 + r];
                float g_l1 = v_col[base3 + NPTS + r];
                float g_l2 = v_col[base3 + 2*NPTS + r];
                float g_o  = v_op[base1 + r];
                float p00 = conics[base3 + n];
                float p01 = conics[base3 + NPTS + n];
                float p11 = conics[base3 + 2*NPTS + n];
                // v_covar2d = -P (v_ci) P   (symmetric)
                float a00 = g_c0, a01 = 0.5f*g_c1, a11 = g_c2;
                float q00 = a00*p00 + a01*p01, q01 = a00*p01 + a01*p11;
                float q10 = a01*p00 + a11*p01, q11 = a01*p01 + a11*p11;
                float u00 = -(p00*q00 + p01*q10), u01 = -(p00*q01 + p01*q11);
                float u10 = -(p01*q00 + p11*q10), u11 = -(p01*q01 + p11*q11);
                // mean_c
                float mx = V00*mn0 + V01*mn1 + V02*mn2 + t0;
                float my = V10*mn0 + V11*mn1 + V12*mn2 + t1;
                float tz = V20*mn0 + V21*mn1 + V22*mn2 + t2;
                float rz = 1.0f / tz;
                float rz2 = rz*rz, rz3 = rz2*rz;
                // T = Rv @ covars ; covar_c = T @ Rv^T (sym)
                float T00 = V00*cv00 + V01*cv01 + V02*cv02;
                float T01 = V00*cv01 + V01*cv11 + V02*cv12;
                float T02 = V00*cv02 + V01*cv12 + V02*cv22;
                float T10 = V10*cv00 + V11*cv01 + V12*cv02;
                float T11 = V10*cv01 + V11*cv11 + V12*cv12;
                float T12 = V10*cv02 + V11*cv12 + V12*cv22;
                float T20 = V20*cv00 + V21*cv01 + V22*cv02;
                float T21 = V20*cv01 + V21*cv11 + V22*cv12;
                float T22 = V20*cv02 + V21*cv12 + V22*cv22;
                float cc00 = T00*V00 + T01*V01 + T02*V02;
                float cc01 = T00*V10 + T01*V11 + T02*V12;
                float cc02 = T00*V20 + T01*V21 + T02*V22;
                float cc11 = T10*V10 + T11*V11 + T12*V12;
                float cc12 = T10*V20 + T11*V21 + T12*V22;
                float cc22 = T20*V20 + T21*V21 + T22*V22;
                // J terms
                float mxz = mx*rz, myz = my*rz;
                float xf = (mxz <= lxp && mxz >= -lxn) ? 1.f : 0.f;
                float yf = (myz <= lyp && myz >= -lyn) ? 1.f : 0.f;
                float tx = tz * fminf(fmaxf(mxz, -lxn), lxp);
                float ty = tz * fminf(fmaxf(myz, -lyn), lyp);
                float j00 = fx*rz, j02 = -fx*tx*rz2;
                float j11 = fy*rz, j12 = -fy*ty*rz2;
                // D = J^T U J ; S = D + D^T
                float W0a = u00*j00, W0b = u01*j11, W0c = u00*j02 + u01*j12;
                float W1a = u10*j00, W1b = u11*j11, W1c = u10*j02 + u11*j12;
                float d00 = j00*W0a, d01 = j00*W0b, d02 = j00*W0c;
                float d10 = j11*W1a, d11 = j11*W1b, d12 = j11*W1c;
                float d20 = j02*W0a + j12*W1a, d21 = j02*W0b + j12*W1b, d22 = j02*W0c + j12*W1c;
                float s00 = d00+d00, s01 = d01+d10, s02 = d02+d20;
                float s11 = d11+d11, s12 = d12+d21, s22 = d22+d22;
                // v_J = (2U) J covar_c
                float e00 = u00+u00, e01 = u01+u10, e11 = u11+u11;
                float X00 = e00*j00, X01 = e01*j11, X02 = e00*j02 + e01*j12;
                float X10 = e01*j00, X11 = e11*j11, X12 = e01*j02 + e11*j12;
                float vJ00 = X00*cc00 + X01*cc01 + X02*cc02;
                float vJ02 = X00*cc02 + X01*cc12 + X02*cc22;
                float vJ11 = X10*cc01 + X11*cc11 + X12*cc12;
                float vJ12 = X10*cc02 + X11*cc12 + X12*cc22;
                // v_mean_c
                float m0 = fx*rz*g_m0;
                float m1 = fy*rz*g_m1;
                float m2 = -(fx*mx*g_m0 + fy*my*g_m1)*rz2;
                m0 -= fx*rz2*vJ02*xf;
                m2 -= fx*rz3*vJ02*tx*(1.f - xf);
                m1 -= fy*rz2*vJ12*yf;
                m2 -= fy*rz3*vJ12*ty*(1.f - yf);
                m2 += -fx*rz2*vJ00 - fy*rz2*vJ11 + 2.f*fx*tx*rz3*vJ02 + 2.f*fy*ty*rz3*vJ12;
                m2 += g_d;
                // v_pW += Rv^T v_mean_c
                vpw0 += V00*m0 + V10*m1 + V20*m2;
                vpw1 += V01*m0 + V11*m1 + V21*m2;
                vpw2 += V02*m0 + V12*m1 + V22*m2;
                // v_Rview += vmc ⊗ mean + S @ T
                rv[c][0] += m0*mn0 + (s00*T00 + s01*T10 + s02*T20);
                rv[c][1] += m0*mn1 + (s00*T01 + s01*T11 + s02*T21);
                rv[c][2] += m0*mn2 + (s00*T02 + s01*T12 + s02*T22);
                rv[c][3] += m1*mn0 + (s01*T00 + s11*T10 + s12*T20);
                rv[c][4] += m1*mn1 + (s01*T01 + s11*T11 + s12*T21);
                rv[c][5] += m1*mn2 + (s01*T02 + s11*T12 + s12*T22);
                rv[c][6] += m2*mn0 + (s02*T00 + s12*T10 + s22*T20);
                rv[c][7] += m2*mn1 + (s02*T01 + s12*T11 + s22*T21);
                rv[c][8] += m2*mn2 + (s02*T02 + s12*T12 + s22*T22);
                // H += Rv^T S Rv
                float P00 = s00*V00 + s01*V10 + s02*V20;
                float P01 = s00*V01 + s01*V11 + s02*V21;
                float P02 = s00*V02 + s01*V12 + s02*V22;
                float P10 = s01*V00 + s11*V10 + s12*V20;
                float P11 = s01*V01 + s11*V11 + s12*V21;
                float P12 = s01*V02 + s11*V12 + s12*V22;
                float P20 = s02*V00 + s12*V10 + s22*V20;
                float P21 = s02*V01 + s12*V11 + s22*V21;
                float P22 = s02*V02 + s12*V12 + s22*V22;
                H00 += V00*P00 + V10*P10 + V20*P20;
                H01 += V00*P01 + V10*P11 + V20*P21;
                H02 += V00*P02 + V10*P12 + V20*P22;
                H11 += V01*P01 + V11*P11 + V21*P21;
                H12 += V01*P02 + V11*P12 + V21*P22;
                H22 += V02*P02 + V12*P12 + V22*P22;
                vcl0 += g_l0; vcl1 += g_l1; vcl2 += g_l2; vopo += g_o;
            }
        }
    }

    // ---- block-reduce v_Rview (36 values per b) ----
#pragma unroll
    for (int off = 32; off >= 1; off >>= 1) {
#pragma unroll
        for (int c = 0; c < 4; c++)
#pragma unroll
            for (int k = 0; k < 9; k++)
                rv[c][k] += __shfl_down(rv[c][k], off, 64);
    }
    __shared__ float redbuf[4][36];
    const int lane = threadIdx.x & 63, wv = threadIdx.x >> 6;
    if (lane == 0) {
#pragma unroll
        for (int c = 0; c < 4; c++)
#pragma unroll
            for (int k = 0; k < 9; k++) redbuf[wv][c*9 + k] = rv[c][k];
    }
    __syncthreads();
    if (threadIdx.x < 36) {
        float s = redbuf[0][threadIdx.x] + redbuf[1][threadIdx.x] +
                  redbuf[2][threadIdx.x] + redbuf[3][threadIdx.x];
        atomicAdd(&rview_acc[b*36 + threadIdx.x], s);
    }

    if (act) {
        // v_M = H @ Mm
        float vM00 = H00*M00 + H01*M10 + H02*M20;
        float vM01 = H00*M01 + H01*M11 + H02*M21;
        float vM02 = H00*M02 + H01*M12 + H02*M22;
        float vM10 = H01*M00 + H11*M10 + H12*M20;
        float vM11 = H01*M01 + H11*M11 + H12*M21;
        float vM12 = H01*M02 + H11*M12 + H12*M22;
        float vM20 = H02*M00 + H12*M10 + H22*M20;
        float vM21 = H02*M01 + H12*M11 + H22*M21;
        float vM22 = H02*M02 + H12*M12 + H22*M22;
        float vs0 = R00*vM00 + R10*vM10 + R20*vM20;
        float vs1 = R01*vM01 + R11*vM11 + R21*vM21;
        float vs2 = R02*vM02 + R12*vM12 + R22*vM22;
        // v_Rrot = vM * scale (per column) ; quat vjp
        float G00 = vM00*sc0, G01 = vM01*sc1, G02 = vM02*sc2;
        float G10 = vM10*sc0, G11 = vM11*sc1, G12 = vM12*sc2;
        float G20 = vM20*sc0, G21 = vM21*sc1, G22 = vM22*sc2;
        float a_ = G21 - G12, b_ = G02 - G20, c_ = G10 - G01;
        float s1122 = G11 + G22, s0022 = G00 + G22, s0011 = G00 + G11;
        float pp01 = G10 + G01, pp02 = G20 + G02, pp12 = G21 + G12;
        float vq0 = 2.f*(qx*a_ + qy*b_ + qz*c_);
        float vq1 = 2.f*(-2.f*qx*s1122 + qy*pp01 + qz*pp02 + qw*a_);
        float vq2 = 2.f*(qx*pp01 - 2.f*qy*s0022 + qz*pp12 + qw*b_);
        float vq3 = 2.f*(qx*pp02 + qy*pp12 - 2.f*qz*s0011 + qw*c_);
        float dot = vq0*qw + vq1*qx + vq2*qy + vq3*qz;
        float o0 = (vq0 - dot*qw)*inv_norm;
        float o1 = (vq1 - dot*qx)*inv_norm;
        float o2 = (vq2 - dot*qy)*inv_norm;
        float o3 = (vq3 - dot*qz)*inv_norm;

        const int pwb = b*NPTS + n;
        out[O_PW + pwb*3 + 0] = vpw0;
        out[O_PW + pwb*3 + 1] = vpw1;
        out[O_PW + pwb*3 + 2] = vpw2;
        float4 qv = make_float4(o0, o1, o2, o3);
        *reinterpret_cast<float4*>(out + O_QU + pwb*4) = qv;
        out[O_SC + pwb*3 + 0] = vs0;
        out[O_SC + pwb*3 + 1] = vs1;
        out[O_SC + pwb*3 + 2] = vs2;
        out[O_CL + (b*3+0)*NPTS + n] = vcl0;
        out[O_CL + (b*3+1)*NPTS + n] = vcl1;
        out[O_CL + (b*3+2)*NPTS + n] = vcl2;
        out[O_OP + b*NPTS + n] = vopo;
    }
}

// ---------- kernel 3: finalize v_Rview ----------
__global__ void fin_kernel(const float* __restrict__ acc, float* __restrict__ out) {
    int t = threadIdx.x;
    if (t < 72) out[4000000 + t] = acc[t];
}

extern "C" void kernel_launch(void* const* d_in, const int* in_sizes, int n_in,
                              void* d_out, int out_size, void* d_ws, size_t ws_size,
                              hipStream_t stream) {
    (void)in_sizes; (void)n_in; (void)out_size; (void)ws_size;
    const float* means    = (const float*)d_in[0];
    const float* quats    = (const float*)d_in[1];
    const float* scales   = (const float*)d_in[2];
    const float* conics   = (const float*)d_in[3];
    const float* viewmats = (const float*)d_in[4];
    const float* Ks       = (const float*)d_in[5];
    const float* v_m2d    = (const float*)d_in[6];
    const float* v_dep    = (const float*)d_in[7];
    const float* v_con    = (const float*)d_in[8];
    const float* v_col    = (const float*)d_in[9];
    const float* v_op     = (const float*)d_in[10];
    const int* mask = (const int*)d_in[11];
    const int* pw   = (const int*)d_in[12];
    const int* ph   = (const int*)d_in[13];
    float* out = (float*)d_out;

    char* ws = (char*)d_ws;
    int*   prefix = (int*)ws;                     // 8*25000*4 = 800000 B
    float* rview  = (float*)(ws + 800000);        // 72*4 = 288 B
    float* cam    = (float*)(ws + 800000 + 288);  // 8*20*4 = 640 B

    scan_kernel<<<dim3(8), dim3(1024), 0, stream>>>(mask, prefix, rview, cam, viewmats, Ks, pw, ph);
    main_kernel<<<dim3((NPTS + 255) / 256, 2), dim3(256), 0, stream>>>(
        means, quats, scales, conics, v_m2d, v_dep, v_con, v_col, v_op,
        mask, prefix, cam, rview, out);
    fin_kernel<<<dim3(1), dim3(128), 0, stream>>>(rview, out);
}

// Round 3
// 169.148 us; speedup vs baseline: 1.2521x; 1.2521x over previous
//
#include <hip/hip_runtime.h>

#define NPTS 200000
#define MWORDS 25000
#define NCHUNK 98          // ceil(25000/256)
#define NSLOT 64

// ---------- workspace layout (bytes) ----------
// prefix    : 8*25000*4 = 800000
// blocksum  : 8*98*4    = 3136
// chunkpref : 8*98*4    = 3136
// slots     : 64*72*4   = 18432
// cam       : 8*20*4    = 640
#define WS_PREFIX    0
#define WS_BLOCKSUM  800000
#define WS_CHUNKPREF 803136
#define WS_SLOTS     806272
#define WS_CAM       824704

// ---------- kernel P1: per-chunk local exclusive scan of popcounts ----------
__global__ __launch_bounds__(256) void scan1_kernel(const int* __restrict__ mask,
                                                    int* __restrict__ prefix,
                                                    int* __restrict__ blocksum) {
    const int bc    = blockIdx.y;           // 0..7
    const int chunk = blockIdx.x;           // 0..97
    const int tid   = threadIdx.x;          // 0..255
    const int lane  = tid & 63, wv = tid >> 6;
    const int w = chunk * 256 + tid;
    const int base = bc * MWORDS;

    int p = (w < MWORDS) ? __popc(mask[base + w]) : 0;
    // inclusive scan within wave
    int v = p;
#pragma unroll
    for (int off = 1; off < 64; off <<= 1) {
        int u = __shfl_up(v, off, 64);
        if (lane >= off) v += u;
    }
    __shared__ int wsum[4];
    if (lane == 63) wsum[wv] = v;
    __syncthreads();
    int wadd = 0;
#pragma unroll
    for (int i = 0; i < 4; i++) if (i < wv) wadd += wsum[i];
    int excl = v - p + wadd;
    if (w < MWORDS) prefix[base + w] = excl;
    if (tid == 255) blocksum[bc * NCHUNK + chunk] = wadd + v;
}

// ---------- kernel P2: scan chunk sums + camera constants + zero slots ----------
__global__ __launch_bounds__(1024) void scan2_kernel(const int* __restrict__ blocksum,
                                                     int* __restrict__ chunkpref,
                                                     float* __restrict__ slots,
                                                     float* __restrict__ cam,
                                                     const float* __restrict__ viewmats,
                                                     const float* __restrict__ Ks,
                                                     const int* __restrict__ pw,
                                                     const int* __restrict__ ph) {
    const int tid = threadIdx.x;
    __shared__ int s[8 * NCHUNK];
    if (tid < 8 * NCHUNK) s[tid] = blocksum[tid];
    __syncthreads();
    if (tid < 8) {
        int running = 0;
        for (int j = 0; j < NCHUNK; j++) {
            int idx = tid * NCHUNK + j;
            int t = s[idx];
            s[idx] = running;
            running += t;
        }
    }
    __syncthreads();
    if (tid < 8 * NCHUNK) chunkpref[tid] = s[tid];

    for (int i = tid; i < NSLOT * 72; i += 1024) slots[i] = 0.f;

    if (tid < 8) {
        const int bc = tid;
        float* cp = cam + bc * 20;
        const int vbase = bc * 16;
        for (int i = 0; i < 3; i++) {
            for (int j = 0; j < 3; j++) cp[i*3 + j] = viewmats[vbase + i*4 + j];
            cp[9 + i] = viewmats[vbase + i*4 + 3];
        }
        const int kbase = bc * 9;
        float fx = Ks[kbase + 0], fy = Ks[kbase + 4];
        float cx = Ks[kbase + 2], cy = Ks[kbase + 5];
        int wi = *pw, hi = *ph;
        float W = (wi >= 1 && wi <= (1 << 20)) ? (float)wi : __int_as_float(wi);
        float H = (hi >= 1 && hi <= (1 << 20)) ? (float)hi : __int_as_float(hi);
        float tanx = 0.5f * W / fx, tany = 0.5f * H / fy;
        cp[12] = fx; cp[13] = fy;
        cp[14] = (W - cx) / fx + 0.3f * tanx;   // lim_x_pos
        cp[15] = cx / fx + 0.3f * tanx;         // lim_x_neg
        cp[16] = (H - cy) / fy + 0.3f * tany;   // lim_y_pos
        cp[17] = cy / fy + 0.3f * tany;         // lim_y_neg
    }
}

// ---------- kernel 2: main backward ----------
__global__ __launch_bounds__(256) void main_kernel(
    const float* __restrict__ means,
    const float* __restrict__ quats,
    const float* __restrict__ scales,
    const float* __restrict__ conics,
    const float* __restrict__ v_m2d,
    const float* __restrict__ v_dep,
    const float* __restrict__ v_con,
    const float* __restrict__ v_col,
    const float* __restrict__ v_op,
    const int* __restrict__ mask,
    const int* __restrict__ prefix,
    const int* __restrict__ chunkpref,
    const float* __restrict__ cam,
    float* __restrict__ slots,
    float* __restrict__ out)
{
    const int O_PW = 0, O_QU = 1200000, O_SC = 2800000, O_CL = 4000072, O_OP = 5200072;
    const int b = blockIdx.y;
    const int n = blockIdx.x * 256 + threadIdx.x;
    const bool act = (n < NPTS);

    float rv[4][9];
#pragma unroll
    for (int c = 0; c < 4; c++)
#pragma unroll
        for (int k = 0; k < 9; k++) rv[c][k] = 0.f;

    float H00=0,H01=0,H02=0,H11=0,H12=0,H22=0;
    float vpw0=0,vpw1=0,vpw2=0;
    float vcl0=0,vcl1=0,vcl2=0, vopo=0;
    float qw=0,qx=0,qy=0,qz=0, inv_norm=1.f;
    float R00=0,R01=0,R02=0,R10=0,R11=0,R12=0,R20=0,R21=0,R22=0;
    float M00=0,M01=0,M02=0,M10=0,M11=0,M12=0,M20=0,M21=0,M22=0;
    float cv00=0,cv01=0,cv02=0,cv11=0,cv12=0,cv22=0;
    float mn0=0,mn1=0,mn2=0, sc0=0,sc1=0,sc2=0;

    if (act) {
        // hoisted: issue all 4 cameras' mask/prefix loads up front (ILP)
        const int w_ = n >> 3, bit = n & 7, chk = w_ >> 8;
        int words[4], pref[4];
#pragma unroll
        for (int c = 0; c < 4; c++) {
            const int bc = b*4 + c;
            words[c] = mask[bc*MWORDS + w_];
            pref[c]  = prefix[bc*MWORDS + w_] + chunkpref[bc*NCHUNK + chk];
        }

        mn0 = means[(b*3+0)*NPTS + n];
        mn1 = means[(b*3+1)*NPTS + n];
        mn2 = means[(b*3+2)*NPTS + n];
        float q0 = quats[(b*4+0)*NPTS + n];
        float q1 = quats[(b*4+1)*NPTS + n];
        float q2 = quats[(b*4+2)*NPTS + n];
        float q3 = quats[(b*4+3)*NPTS + n];
        sc0 = scales[(b*3+0)*NPTS + n];
        sc1 = scales[(b*3+1)*NPTS + n];
        sc2 = scales[(b*3+2)*NPTS + n];
        inv_norm = rsqrtf(q0*q0 + q1*q1 + q2*q2 + q3*q3);
        qw = q0*inv_norm; qx = q1*inv_norm; qy = q2*inv_norm; qz = q3*inv_norm;
        R00 = 1.f - 2.f*(qy*qy + qz*qz); R01 = 2.f*(qx*qy - qw*qz); R02 = 2.f*(qx*qz + qw*qy);
        R10 = 2.f*(qx*qy + qw*qz); R11 = 1.f - 2.f*(qx*qx + qz*qz); R12 = 2.f*(qy*qz - qw*qx);
        R20 = 2.f*(qx*qz - qw*qy); R21 = 2.f*(qy*qz + qw*qx); R22 = 1.f - 2.f*(qx*qx + qy*qy);
        M00 = R00*sc0; M01 = R01*sc1; M02 = R02*sc2;
        M10 = R10*sc0; M11 = R11*sc1; M12 = R12*sc2;
        M20 = R20*sc0; M21 = R21*sc1; M22 = R22*sc2;
        cv00 = M00*M00 + M01*M01 + M02*M02;
        cv01 = M00*M10 + M01*M11 + M02*M12;
        cv02 = M00*M20 + M01*M21 + M02*M22;
        cv11 = M10*M10 + M11*M11 + M12*M12;
        cv12 = M10*M20 + M11*M21 + M12*M22;
        cv22 = M20*M20 + M21*M21 + M22*M22;

#pragma unroll
        for (int c = 0; c < 4; c++) {
            const int bc = b*4 + c;
            const float* cp = cam + bc*20;
            const float V00=cp[0],V01=cp[1],V02=cp[2],V10=cp[3],V11=cp[4],V12=cp[5],V20=cp[6],V21=cp[7],V22=cp[8];
            const float t0=cp[9], t1=cp[10], t2=cp[11];
            const float fx=cp[12], fy=cp[13], lxp=cp[14], lxn=cp[15], lyp=cp[16], lyn=cp[17];
            const int word = words[c];
            if ((word >> bit) & 1) {
                const int r = pref[c] + __popc(word & ((1 << bit) - 1));
                const int base3 = bc*3*NPTS, base2 = bc*2*NPTS, base1 = bc*NPTS;
                float g_c0 = v_con[base3 + r];
                float g_c1 = v_con[base3 + NPTS + r];
                float g_c2 = v_con[base3 + 2*NPTS + r];
                float g_m0 = v_m2d[base2 + r];
                float g_m1 = v_m2d[base2 + NPTS + r];
                float g_d  = v_dep[base1 + r];
                float g_l0 = v_col[base3 + r];
                float g_l1 = v_col[base3 + NPTS + r];
                float g_l2 = v_col[base3 + 2*NPTS + r];
                float g_o  = v_op[base1 + r];
                float p00 = conics[base3 + n];
                float p01 = conics[base3 + NPTS + n];
                float p11 = conics[base3 + 2*NPTS + n];
                // v_covar2d = -P (v_ci) P   (symmetric)
                float a00 = g_c0, a01 = 0.5f*g_c1, a11 = g_c2;
                float q00 = a00*p00 + a01*p01, q01 = a00*p01 + a01*p11;
                float q10 = a01*p00 + a11*p01, q11 = a01*p01 + a11*p11;
                float u00 = -(p00*q00 + p01*q10), u01 = -(p00*q01 + p01*q11);
                float u10 = -(p01*q00 + p11*q10), u11 = -(p01*q01 + p11*q11);
                // mean_c
                float mx = V00*mn0 + V01*mn1 + V02*mn2 + t0;
                float my = V10*mn0 + V11*mn1 + V12*mn2 + t1;
                float tz = V20*mn0 + V21*mn1 + V22*mn2 + t2;
                float rz = 1.0f / tz;
                float rz2 = rz*rz, rz3 = rz2*rz;
                // T = Rv @ covars ; covar_c = T @ Rv^T (sym)
                float T00 = V00*cv00 + V01*cv01 + V02*cv02;
                float T01 = V00*cv01 + V01*cv11 + V02*cv12;
                float T02 = V00*cv02 + V01*cv12 + V02*cv22;
                float T10 = V10*cv00 + V11*cv01 + V12*cv02;
                float T11 = V10*cv01 + V11*cv11 + V12*cv12;
                float T12 = V10*cv02 + V11*cv12 + V12*cv22;
                float T20 = V20*cv00 + V21*cv01 + V22*cv02;
                float T21 = V20*cv01 + V21*cv11 + V22*cv12;
                float T22 = V20*cv02 + V21*cv12 + V22*cv22;
                float cc00 = T00*V00 + T01*V01 + T02*V02;
                float cc01 = T00*V10 + T01*V11 + T02*V12;
                float cc02 = T00*V20 + T01*V21 + T02*V22;
                float cc11 = T10*V10 + T11*V11 + T12*V12;
                float cc12 = T10*V20 + T11*V21 + T12*V22;
                float cc22 = T20*V20 + T21*V21 + T22*V22;
                // J terms
                float mxz = mx*rz, myz = my*rz;
                float xf = (mxz <= lxp && mxz >= -lxn) ? 1.f : 0.f;
                float yf = (myz <= lyp && myz >= -lyn) ? 1.f : 0.f;
                float tx = tz * fminf(fmaxf(mxz, -lxn), lxp);
                float ty = tz * fminf(fmaxf(myz, -lyn), lyp);
                float j00 = fx*rz, j02 = -fx*tx*rz2;
                float j11 = fy*rz, j12 = -fy*ty*rz2;
                // D = J^T U J ; S = D + D^T
                float W0a = u00*j00, W0b = u01*j11, W0c = u00*j02 + u01*j12;
                float W1a = u10*j00, W1b = u11*j11, W1c = u10*j02 + u11*j12;
                float d00 = j00*W0a, d01 = j00*W0b, d02 = j00*W0c;
                float d10 = j11*W1a, d11 = j11*W1b, d12 = j11*W1c;
                float d20 = j02*W0a + j12*W1a, d21 = j02*W0b + j12*W1b, d22 = j02*W0c + j12*W1c;
                float s00 = d00+d00, s01 = d01+d10, s02 = d02+d20;
                float s11 = d11+d11, s12 = d12+d21, s22 = d22+d22;
                // v_J = (2U) J covar_c
                float e00 = u00+u00, e01 = u01+u10, e11 = u11+u11;
                float X00 = e00*j00, X01 = e01*j11, X02 = e00*j02 + e01*j12;
                float X10 = e01*j00, X11 = e11*j11, X12 = e01*j02 + e11*j12;
                float vJ00 = X00*cc00 + X01*cc01 + X02*cc02;
                float vJ02 = X00*cc02 + X01*cc12 + X02*cc22;
                float vJ11 = X10*cc01 + X11*cc11 + X12*cc12;
                float vJ12 = X10*cc02 + X11*cc12 + X12*cc22;
                // v_mean_c
                float m0 = fx*rz*g_m0;
                float m1 = fy*rz*g_m1;
                float m2 = -(fx*mx*g_m0 + fy*my*g_m1)*rz2;
                m0 -= fx*rz2*vJ02*xf;
                m2 -= fx*rz3*vJ02*tx*(1.f - xf);
                m1 -= fy*rz2*vJ12*yf;
                m2 -= fy*rz3*vJ12*ty*(1.f - yf);
                m2 += -fx*rz2*vJ00 - fy*rz2*vJ11 + 2.f*fx*tx*rz3*vJ02 + 2.f*fy*ty*rz3*vJ12;
                m2 += g_d;
                // v_pW += Rv^T v_mean_c
                vpw0 += V00*m0 + V10*m1 + V20*m2;
                vpw1 += V01*m0 + V11*m1 + V21*m2;
                vpw2 += V02*m0 + V12*m1 + V22*m2;
                // v_Rview += vmc ⊗ mean + S @ T
                rv[c][0] += m0*mn0 + (s00*T00 + s01*T10 + s02*T20);
                rv[c][1] += m0*mn1 + (s00*T01 + s01*T11 + s02*T21);
                rv[c][2] += m0*mn2 + (s00*T02 + s01*T12 + s02*T22);
                rv[c][3] += m1*mn0 + (s01*T00 + s11*T10 + s12*T20);
                rv[c][4] += m1*mn1 + (s01*T01 + s11*T11 + s12*T21);
                rv[c][5] += m1*mn2 + (s01*T02 + s11*T12 + s12*T22);
                rv[c][6] += m2*mn0 + (s02*T00 + s12*T10 + s22*T20);
                rv[c][7] += m2*mn1 + (s02*T01 + s12*T11 + s22*T21);
                rv[c][8] += m2*mn2 + (s02*T02 + s12*T12 + s22*T22);
                // H += Rv^T S Rv
                float P00 = s00*V00 + s01*V10 + s02*V20;
                float P01 = s00*V01 + s01*V11 + s02*V21;
                float P02 = s00*V02 + s01*V12 + s02*V22;
                float P10 = s01*V00 + s11*V10 + s12*V20;
                float P11 = s01*V01 + s11*V11 + s12*V21;
                float P12 = s01*V02 + s11*V12 + s12*V22;
                float P20 = s02*V00 + s12*V10 + s22*V20;
                float P21 = s02*V01 + s12*V11 + s22*V21;
                float P22 = s02*V02 + s12*V12 + s22*V22;
                H00 += V00*P00 + V10*P10 + V20*P20;
                H01 += V00*P01 + V10*P11 + V20*P21;
                H02 += V00*P02 + V10*P12 + V20*P22;
                H11 += V01*P01 + V11*P11 + V21*P21;
                H12 += V01*P02 + V11*P12 + V21*P22;
                H22 += V02*P02 + V12*P12 + V22*P22;
                vcl0 += g_l0; vcl1 += g_l1; vcl2 += g_l2; vopo += g_o;
            }
        }
    }

    // ---- block-reduce v_Rview (36 values per b) ----
#pragma unroll
    for (int off = 32; off >= 1; off >>= 1) {
#pragma unroll
        for (int c = 0; c < 4; c++)
#pragma unroll
            for (int k = 0; k < 9; k++)
                rv[c][k] += __shfl_down(rv[c][k], off, 64);
    }
    __shared__ float redbuf[4][36];
    const int lane = threadIdx.x & 63, wv = threadIdx.x >> 6;
    if (lane == 0) {
#pragma unroll
        for (int c = 0; c < 4; c++)
#pragma unroll
            for (int k = 0; k < 9; k++) redbuf[wv][c*9 + k] = rv[c][k];
    }
    __syncthreads();
    if (threadIdx.x < 36) {
        float s = redbuf[0][threadIdx.x] + redbuf[1][threadIdx.x] +
                  redbuf[2][threadIdx.x] + redbuf[3][threadIdx.x];
        const int slot = blockIdx.x & (NSLOT - 1);
        atomicAdd(&slots[slot*72 + b*36 + threadIdx.x], s);
    }

    if (act) {
        // v_M = H @ Mm
        float vM00 = H00*M00 + H01*M10 + H02*M20;
        float vM01 = H00*M01 + H01*M11 + H02*M21;
        float vM02 = H00*M02 + H01*M12 + H02*M22;
        float vM10 = H01*M00 + H11*M10 + H12*M20;
        float vM11 = H01*M01 + H11*M11 + H12*M21;
        float vM12 = H01*M02 + H11*M12 + H12*M22;
        float vM20 = H02*M00 + H12*M10 + H22*M20;
        float vM21 = H02*M01 + H12*M11 + H22*M21;
        float vM22 = H02*M02 + H12*M12 + H22*M22;
        float vs0 = R00*vM00 + R10*vM10 + R20*vM20;
        float vs1 = R01*vM01 + R11*vM11 + R21*vM21;
        float vs2 = R02*vM02 + R12*vM12 + R22*vM22;
        // v_Rrot = vM * scale (per column) ; quat vjp
        float G00 = vM00*sc0, G01 = vM01*sc1, G02 = vM02*sc2;
        float G10 = vM10*sc0, G11 = vM11*sc1, G12 = vM12*sc2;
        float G20 = vM20*sc0, G21 = vM21*sc1, G22 = vM22*sc2;
        float a_ = G21 - G12, b_ = G02 - G20, c_ = G10 - G01;
        float s1122 = G11 + G22, s0022 = G00 + G22, s0011 = G00 + G11;
        float pp01 = G10 + G01, pp02 = G20 + G02, pp12 = G21 + G12;
        float vq0 = 2.f*(qx*a_ + qy*b_ + qz*c_);
        float vq1 = 2.f*(-2.f*qx*s1122 + qy*pp01 + qz*pp02 + qw*a_);
        float vq2 = 2.f*(qx*pp01 - 2.f*qy*s0022 + qz*pp12 + qw*b_);
        float vq3 = 2.f*(qx*pp02 + qy*pp12 - 2.f*qz*s0011 + qw*c_);
        float dot = vq0*qw + vq1*qx + vq2*qy + vq3*qz;
        float o0 = (vq0 - dot*qw)*inv_norm;
        float o1 = (vq1 - dot*qx)*inv_norm;
        float o2 = (vq2 - dot*qy)*inv_norm;
        float o3 = (vq3 - dot*qz)*inv_norm;

        const int pwb = b*NPTS + n;
        out[O_PW + pwb*3 + 0] = vpw0;
        out[O_PW + pwb*3 + 1] = vpw1;
        out[O_PW + pwb*3 + 2] = vpw2;
        float4 qv = make_float4(o0, o1, o2, o3);
        *reinterpret_cast<float4*>(out + O_QU + pwb*4) = qv;
        out[O_SC + pwb*3 + 0] = vs0;
        out[O_SC + pwb*3 + 1] = vs1;
        out[O_SC + pwb*3 + 2] = vs2;
        out[O_CL + (b*3+0)*NPTS + n] = vcl0;
        out[O_CL + (b*3+1)*NPTS + n] = vcl1;
        out[O_CL + (b*3+2)*NPTS + n] = vcl2;
        out[O_OP + b*NPTS + n] = vopo;
    }
}

// ---------- kernel 3: finalize v_Rview ----------
__global__ void fin_kernel(const float* __restrict__ slots, float* __restrict__ out) {
    int t = threadIdx.x;
    if (t < 72) {
        float s = 0.f;
#pragma unroll
        for (int i = 0; i < NSLOT; i++) s += slots[i*72 + t];
        out[4000000 + t] = s;
    }
}

extern "C" void kernel_launch(void* const* d_in, const int* in_sizes, int n_in,
                              void* d_out, int out_size, void* d_ws, size_t ws_size,
                              hipStream_t stream) {
    (void)in_sizes; (void)n_in; (void)out_size; (void)ws_size;
    const float* means    = (const float*)d_in[0];
    const float* quats    = (const float*)d_in[1];
    const float* scales   = (const float*)d_in[2];
    const float* conics   = (const float*)d_in[3];
    const float* viewmats = (const float*)d_in[4];
    const float* Ks       = (const float*)d_in[5];
    const float* v_m2d    = (const float*)d_in[6];
    const float* v_dep    = (const float*)d_in[7];
    const float* v_con    = (const float*)d_in[8];
    const float* v_col    = (const float*)d_in[9];
    const float* v_op     = (const float*)d_in[10];
    const int* mask = (const int*)d_in[11];
    const int* pw   = (const int*)d_in[12];
    const int* ph   = (const int*)d_in[13];
    float* out = (float*)d_out;

    char* ws = (char*)d_ws;
    int*   prefix    = (int*)(ws + WS_PREFIX);
    int*   blocksum  = (int*)(ws + WS_BLOCKSUM);
    int*   chunkpref = (int*)(ws + WS_CHUNKPREF);
    float* slots     = (float*)(ws + WS_SLOTS);
    float* cam       = (float*)(ws + WS_CAM);

    scan1_kernel<<<dim3(NCHUNK, 8), dim3(256), 0, stream>>>(mask, prefix, blocksum);
    scan2_kernel<<<dim3(1), dim3(1024), 0, stream>>>(blocksum, chunkpref, slots, cam,
                                                     viewmats, Ks, pw, ph);
    main_kernel<<<dim3((NPTS + 255) / 256, 2), dim3(256), 0, stream>>>(
        means, quats, scales, conics, v_m2d, v_dep, v_con, v_col, v_op,
        mask, prefix, chunkpref, cam, slots, out);
    fin_kernel<<<dim3(1), dim3(128), 0, stream>>>(slots, out);
}